// Round 3
// baseline (1088.074 us; speedup 1.0000x reference)
//
#include <hip/hip_runtime.h>
#include <hip/hip_fp16.h>
#include <math.h>
#include <stdint.h>

#define Bb 8
#define Ss 512
#define Dd 768
#define Hh 12
#define Ee 8
#define DFF 3072
#define MROWS 4096          // B*S
#define QKVN 2304           // H*3*DH

static __device__ const float SCALE_ = 0.036084391824351615f; // 768^-0.5

typedef short bf8_t __attribute__((ext_vector_type(8)));
typedef _Float16 f16x4_t __attribute__((ext_vector_type(4)));
typedef float f32x4_t __attribute__((ext_vector_type(4)));

__device__ __forceinline__ float bf2f(unsigned short u){
  union { unsigned int i; float f; } x; x.i = ((unsigned int)u)<<16; return x.f;
}
__device__ __forceinline__ unsigned short f2bf(float f){
  union { float f; unsigned int i; } x; x.f = f;
  unsigned int u = x.i;
  return (unsigned short)((u + 0x7fffu + ((u>>16)&1u)) >> 16);
}

// async global->LDS, 16B per lane; LDS dest is wave-uniform base + lane*16
__device__ __forceinline__ void gl_lds16(const void* g, void* l){
  __builtin_amdgcn_global_load_lds(
      (const __attribute__((address_space(1))) unsigned int*)(g),
      (__attribute__((address_space(3))) unsigned int*)(uintptr_t)(l),
      16, 0, 0);
}

// ---------------- cast fp32 -> bf16 (n % 4 == 0) ----------------
__global__ void cast_kernel(const float* __restrict__ in, unsigned short* __restrict__ out, int n){
  int i = (blockIdx.x*256 + threadIdx.x)*4;
  if (i >= n) return;
  const float4 v = *(const float4*)(in + i);
  ushort4 o; o.x=f2bf(v.x); o.y=f2bf(v.y); o.z=f2bf(v.z); o.w=f2bf(v.w);
  *(ushort4*)(out + i) = o;
}

// ---------------- GEMM: C = A(MxK) * B(NxK)^T, 128x128 tile, 4 waves ----------------
// MODE 0: A bf16, B bf16, no bias, store bf16, z-batched            (QKV)
// MODE 1: A bf16, B bf16, bias, store bf16, feat accum, z-batched   (dense)
// MODE 2: A bf16, B fp32 (sel-indexed), bias, exact GELU, store bf16 (FFN1)
// MODE 3: A bf16, B fp32 (sel-indexed), bias, store fp32             (FFN2)
// A/B (bf16 modes) staged via global_load_lds dwordx4 into pitch-32 LDS (m97 structure).
template<int MODE>
__global__ __launch_bounds__(256)
void gemm_bt(const unsigned short* __restrict__ A,
             const unsigned short* __restrict__ Bbf,
             const float* __restrict__ Bf32,
             const float* __restrict__ bias,
             void* __restrict__ Cout,
             int K, int N,
             long aStrideZ, long bStrideZ, long cStrideZ, long biasStrideZ,
             const int* __restrict__ sel, long wstride, int bstride,
             float* __restrict__ feat, int e_base)
{
  __shared__ unsigned short As[128*32];
  __shared__ unsigned short Bs[128*40];   // pitch 32 (MODE<2) or 40 (MODE>=2)
  const int rt = blockIdx.y, ct = blockIdx.x, z = blockIdx.z;
  const int t = threadIdx.x;
  const int w = t>>6, l = t&63, q4 = l>>4, mr = l&15;
  const int wm = (w&1)*64, wn = (w>>1)*64;
  const int sr = t>>2, cv = t&3;

  A += (size_t)z * aStrideZ;
  const unsigned short* Bp = Bbf + (size_t)z * bStrideZ;
  const float* Bf_ = Bf32;
  const float* biasp = bias + (size_t)z * biasStrideZ;
  if (MODE >= 2) {
    const int ex = sel[rt>>2];
    Bf_ = Bf32 + (long)ex * wstride;
    biasp = bias + (long)ex * bstride;
  }

  f32x4_t acc[4][4];
  #pragma unroll
  for (int i=0;i<4;i++)
    #pragma unroll
    for (int j=0;j<4;j++) acc[i][j] = (f32x4_t){0.f,0.f,0.f,0.f};

  // staging addresses (per-lane global, per-wave LDS base)
  const unsigned short* gA = A + (size_t)(rt*128 + w*16 + (l>>2))*K + (l&3)*8;
  unsigned short* lA = As + w*512;   // w*1024 bytes
  const unsigned short* gB = nullptr;
  unsigned short* lB = Bs + w*512;
  if (MODE < 2) gB = Bp + (size_t)(ct*128 + w*16 + (l>>2))*K + (l&3)*8;

  for (int k0 = 0; k0 < K; k0 += 32) {
    uint4 b0, b1;
    if (MODE >= 2) {
      const float* Br0 = Bf_ + (long)(ct*128 + sr)*K + cv*8 + k0;
      const float* Br1 = Br0 + (long)64*K;
      float4 f0a = *(const float4*)Br0;  float4 f0b = *(const float4*)(Br0+4);
      float4 f1a = *(const float4*)Br1;  float4 f1b = *(const float4*)(Br1+4);
      union { unsigned short s[8]; uint4 v; } p0, p1;
      p0.s[0]=f2bf(f0a.x); p0.s[1]=f2bf(f0a.y); p0.s[2]=f2bf(f0a.z); p0.s[3]=f2bf(f0a.w);
      p0.s[4]=f2bf(f0b.x); p0.s[5]=f2bf(f0b.y); p0.s[6]=f2bf(f0b.z); p0.s[7]=f2bf(f0b.w);
      p1.s[0]=f2bf(f1a.x); p1.s[1]=f2bf(f1a.y); p1.s[2]=f2bf(f1a.z); p1.s[3]=f2bf(f1a.w);
      p1.s[4]=f2bf(f1b.x); p1.s[5]=f2bf(f1b.y); p1.s[6]=f2bf(f1b.z); p1.s[7]=f2bf(f1b.w);
      b0 = p0.v; b1 = p1.v;
    }
    __syncthreads();   // previous iteration's frag reads done
    gl_lds16(gA + k0,          lA);
    gl_lds16(gA + (size_t)64*K + k0, lA + 2048);
    if (MODE < 2) {
      gl_lds16(gB + k0,          lB);
      gl_lds16(gB + (size_t)64*K + k0, lB + 2048);
    } else {
      *(uint4*)&Bs[sr*40 + cv*8]      = b0;
      *(uint4*)&Bs[(sr+64)*40 + cv*8] = b1;
    }
    __syncthreads();
    const int bpitch = (MODE < 2) ? 32 : 40;
    bf8_t af[4], bfv[4];
    #pragma unroll
    for (int i=0;i<4;i++) af[i]  = *(const bf8_t*)&As[(wm+i*16+mr)*32 + q4*8];
    #pragma unroll
    for (int j=0;j<4;j++) bfv[j] = *(const bf8_t*)&Bs[(wn+j*16+mr)*bpitch + q4*8];
    #pragma unroll
    for (int i=0;i<4;i++)
      #pragma unroll
      for (int j=0;j<4;j++)
        acc[i][j] = __builtin_amdgcn_mfma_f32_16x16x32_bf16(af[i], bfv[j], acc[i][j], 0,0,0);
  }

  const long Cld = N;
  unsigned short* Cb16 = (unsigned short*)Cout + (size_t)z * cStrideZ;
  float* Cf32 = (float*)Cout;
  #pragma unroll
  for (int j=0;j<4;j++){
    const int n = ct*128 + wn + j*16 + mr;
    const float bv = (MODE==0) ? 0.f : biasp[n];
    float colsum = 0.f;
    #pragma unroll
    for (int i=0;i<4;i++){
      const long mbase = (long)rt*128 + wm + i*16 + q4*4;
      #pragma unroll
      for (int r=0;r<4;r++){
        const float v = acc[i][j][r] + bv;
        const long m = mbase + r;
        if (MODE==0) {
          Cb16[m*Cld + n] = f2bf(v);
        } else if (MODE==1) {
          Cb16[m*Cld + n] = f2bf(v);
          colsum += v;
        } else if (MODE==2) {
          const float g = 0.5f*v*(1.0f + erff(v*0.70710678118654752f));
          Cb16[m*Cld + n] = f2bf(g);
        } else {
          Cf32[m*Cld + n] = v;
        }
      }
    }
    if (MODE==1){
      colsum += __shfl_xor(colsum, 16);
      colsum += __shfl_xor(colsum, 32);
      if (q4==0){
        atomicAdd(feat + ((long)(e_base + z)*Bb + (rt>>2))*Dd + n, colsum);
      }
    }
  }
}

// ---------------- attention: per (qblock 64 rows, head, batch[, expert]) workgroup ----------
__global__ __launch_bounds__(256)
void attn_kernel(const unsigned short* __restrict__ qkv,
                 const int* __restrict__ mask,
                 unsigned short* __restrict__ ctx,
                 long qkvStrideZ, long ctxStrideZ)
{
  const int qb = blockIdx.x, h = blockIdx.y;
  const int zz = blockIdx.z;
  const int b = zz & 7, e = zz >> 3;
  qkv += (size_t)e * qkvStrideZ;
  ctx += (size_t)e * ctxStrideZ;

  const int t = threadIdx.x, w = t>>6, l = t&63, q4 = l>>4, mr = l&15;
  __shared__ unsigned short Ks[16*72];   // 16 keys x 64 d (bf16), pitch 72
  __shared__ unsigned short Vs[64*20];   // V^T: 64 d x 16 keys (f16), pitch 20

  const int srow = b*512 + qb*64 + w*16;
  const unsigned short* qp = qkv + (long)(srow+mr)*QKVN + h*192;
  const bf8_t qf0 = *(const bf8_t*)(qp + q4*8);
  const bf8_t qf1 = *(const bf8_t*)(qp + 32 + q4*8);

  f32x4_t cacc[4];
  #pragma unroll
  for (int d=0; d<4; d++) cacc[d] = (f32x4_t){0.f,0.f,0.f,0.f};
  float lsum = 0.f;

  const int el   = t*4;
  const int skey = el>>6;     // 0..15
  const int sd   = el&63;     // multiple of 4

  for (int kt=0; kt<32; kt++){
    const long krow = (long)(b*512 + kt*16 + skey)*QKVN + h*192;
    const uint2 kv = *(const uint2*)(qkv + krow + 64  + sd);
    const uint2 vv = *(const uint2*)(qkv + krow + 128 + sd);
    __syncthreads();   // previous iteration's LDS reads done
    *(uint2*)&Ks[skey*72 + sd] = kv;
    {
      const unsigned short* pv = (const unsigned short*)&vv;
      #pragma unroll
      for (int jj=0;jj<4;jj++){
        const __half hv = __float2half(bf2f(pv[jj]));
        Vs[(sd+jj)*20 + skey] = __half_as_ushort(hv);
      }
    }
    __syncthreads();

    const bf8_t kf0 = *(const bf8_t*)&Ks[mr*72 + q4*8];
    const bf8_t kf1 = *(const bf8_t*)&Ks[mr*72 + 32 + q4*8];
    f32x4_t st = __builtin_amdgcn_mfma_f32_16x16x32_bf16(kf0, qf0, (f32x4_t){0.f,0.f,0.f,0.f}, 0,0,0);
    st = __builtin_amdgcn_mfma_f32_16x16x32_bf16(kf1, qf1, st, 0,0,0);

    f16x4_t pf;
    #pragma unroll
    for (int r=0;r<4;r++){
      const int key = kt*16 + q4*4 + r;
      float p = __expf(st[r]*SCALE_);
      if (mask[b*512 + key] == 0) p = 0.f;
      lsum += p;
      pf[r] = (_Float16)p;
    }
    #pragma unroll
    for (int dblk=0; dblk<4; dblk++){
      const f16x4_t vf = *(const f16x4_t*)&Vs[(dblk*16+mr)*20 + q4*4];
      cacc[dblk] = __builtin_amdgcn_mfma_f32_16x16x16f16(pf, vf, cacc[dblk], 0,0,0);
    }
  }

  lsum += __shfl_xor(lsum, 16);
  lsum += __shfl_xor(lsum, 32);
  #pragma unroll
  for (int r=0;r<4;r++){
    const int m2 = q4*4 + r;
    const float lr = __shfl(lsum, m2);
    const float inv = 1.0f/lr;
    const long orow = (long)(b*512 + qb*64 + w*16 + m2)*Dd + h*64;
    #pragma unroll
    for (int dblk=0; dblk<4; dblk++){
      ctx[orow + dblk*16 + mr] = f2bf(cacc[dblk][r]*inv);
    }
  }
}

// ---------------- routing: dists + argmin ----------------
__global__ void routing_kernel(const float* __restrict__ feat, const float* __restrict__ centers,
                               int* __restrict__ sel)
{
  __shared__ float d2s[64];
  const int t = threadIdx.x;
  if (t < 64){
    const int e = t>>3, b = t&7;
    const float* f = feat + (long)(e*Bb + b)*Dd;
    const float* c = centers + (long)e*Dd;
    float s = 0.f;
    for (int d=0; d<Dd; d++){
      const float df = f[d]*(1.0f/512.0f) - c[d];
      s += df*df;
    }
    d2s[t] = s;
  }
  __syncthreads();
  if (t < 8){
    float best = 3.4e38f; int bi = 0;
    for (int e=0;e<8;e++){ const float v = d2s[e*8+t]; if (v < best){ best=v; bi=e; } }
    sel[t] = bi;
  }
}

// ---------------- h = LN1(att[sel]+x), one wave per row ----------------
__global__ __launch_bounds__(256)
void hprep_kernel(const unsigned short* __restrict__ attall, const float* __restrict__ x,
                  const float* __restrict__ g, const float* __restrict__ be,
                  const int* __restrict__ sel, unsigned short* __restrict__ hbuf)
{
  const int w = threadIdx.x>>6, l = threadIdx.x&63;
  const int row = blockIdx.x*4 + w;
  const int b = row>>9;
  const int e = sel[b];
  const unsigned short* ap = attall + ((long)e*MROWS + row)*Dd;
  const float* xp = x + (long)row*Dd;
  float v[12]; float s = 0.f;
  #pragma unroll
  for (int i=0;i<12;i++){ const int d = i*64 + l; v[i] = bf2f(ap[d]) + xp[d]; s += v[i]; }
  #pragma unroll
  for (int o=32;o>0;o>>=1) s += __shfl_xor(s, o);
  const float mean = s * (1.0f/768.0f);
  float vs = 0.f;
  #pragma unroll
  for (int i=0;i<12;i++){ const float dd = v[i]-mean; vs += dd*dd; }
  #pragma unroll
  for (int o=32;o>0;o>>=1) vs += __shfl_xor(vs, o);
  const float rs = rsqrtf(vs*(1.0f/768.0f) + 1e-12f);
  #pragma unroll
  for (int i=0;i<12;i++){
    const int d = i*64 + l;
    hbuf[(long)row*Dd + d] = f2bf((v[i]-mean)*rs*g[(long)e*Dd+d] + be[(long)e*Dd+d]);
  }
}

// ---------------- out = LN2(h + ffn), one wave per row ----------------
__global__ __launch_bounds__(256)
void ln2_kernel(const unsigned short* __restrict__ hbuf, const float* __restrict__ tbuf,
                const float* __restrict__ g, const float* __restrict__ be,
                const int* __restrict__ sel, float* __restrict__ out)
{
  const int w = threadIdx.x>>6, l = threadIdx.x&63;
  const int row = blockIdx.x*4 + w;
  const int b = row>>9;
  const int e = sel[b];
  const unsigned short* hp = hbuf + (long)row*Dd;
  const float* tp = tbuf + (long)row*Dd;
  float v[12]; float s = 0.f;
  #pragma unroll
  for (int i=0;i<12;i++){ const int d = i*64 + l; v[i] = bf2f(hp[d]) + tp[d]; s += v[i]; }
  #pragma unroll
  for (int o=32;o>0;o>>=1) s += __shfl_xor(s, o);
  const float mean = s * (1.0f/768.0f);
  float vs = 0.f;
  #pragma unroll
  for (int i=0;i<12;i++){ const float dd = v[i]-mean; vs += dd*dd; }
  #pragma unroll
  for (int o=32;o>0;o>>=1) vs += __shfl_xor(vs, o);
  const float rs = rsqrtf(vs*(1.0f/768.0f) + 1e-12f);
  #pragma unroll
  for (int i=0;i<12;i++){
    const int d = i*64 + l;
    out[(long)row*Dd + d] = (v[i]-mean)*rs*g[(long)e*Dd+d] + be[(long)e*Dd+d];
  }
}

// ---------------- launch ----------------
extern "C" void kernel_launch(void* const* d_in, const int* in_sizes, int n_in,
                              void* d_out, int out_size, void* d_ws, size_t ws_size,
                              hipStream_t stream)
{
  const float* x      = (const float*)d_in[0];
  const int*   mask   = (const int*)d_in[1];
  const float* Wqkv   = (const float*)d_in[2];
  const float* Wd     = (const float*)d_in[3];
  const float* bd     = (const float*)d_in[4];
  const float* ln1g   = (const float*)d_in[5];
  const float* ln1b   = (const float*)d_in[6];
  const float* W1     = (const float*)d_in[7];
  const float* b1     = (const float*)d_in[8];
  const float* W2     = (const float*)d_in[9];
  const float* b2     = (const float*)d_in[10];
  const float* ln2g   = (const float*)d_in[11];
  const float* ln2b   = (const float*)d_in[12];
  const float* centers= (const float*)d_in[13];

  char* p = (char*)d_ws;
  auto carve = [&](size_t bytes)->char*{ char* r = p; p += ((bytes + 255) & ~(size_t)255); return r; };

  // decision is a pure function of ws_size (constant) -> graph-capture safe
  const bool batched = ws_size >= 302186752ull + 4096ull;

  unsigned short* xb     = (unsigned short*)carve((size_t)MROWS*Dd*2);        // 6.3 MB
  unsigned short* Wqkvb  = (unsigned short*)carve((size_t)Ee*QKVN*Dd*2);      // 28.3 MB
  unsigned short* Wdb    = (unsigned short*)carve((size_t)Ee*Dd*Dd*2);        // 9.4 MB
  unsigned short* attall = (unsigned short*)carve((size_t)Ee*MROWS*Dd*2);     // 50.3 MB
  float*          feat   = (float*)carve((size_t)Ee*Bb*Dd*4);                 // 0.2 MB
  int*            sel    = (int*)carve(256);
  unsigned short* hbuf   = (unsigned short*)carve((size_t)MROWS*Dd*2);        // 6.3 MB

  cast_kernel<<<(MROWS*Dd/4 + 255)/256, 256, 0, stream>>>(x, xb, MROWS*Dd);
  cast_kernel<<<(Ee*QKVN*Dd/4 + 255)/256, 256, 0, stream>>>(Wqkv, Wqkvb, Ee*QKVN*Dd);
  cast_kernel<<<(Ee*Dd*Dd/4 + 255)/256, 256, 0, stream>>>(Wd, Wdb, Ee*Dd*Dd);
  (void)hipMemsetAsync(feat, 0, (size_t)Ee*Bb*Dd*4, stream);

  if (batched) {
    unsigned short* qkv_all = (unsigned short*)carve((size_t)Ee*MROWS*QKVN*2); // 151 MB
    unsigned short* ctx_all = (unsigned short*)carve((size_t)Ee*MROWS*Dd*2);   // 50.3 MB
    unsigned short* Gbuf = qkv_all;                                   // alias (dead by FFN time)
    float*          tbuf = (float*)((char*)qkv_all + (size_t)MROWS*DFF*2 + 256);

    gemm_bt<0><<<dim3(QKVN/128, MROWS/128, Ee), 256, 0, stream>>>(
        xb, Wqkvb, nullptr, nullptr, qkv_all, Dd, QKVN,
        0, (long)QKVN*Dd, (long)MROWS*QKVN, 0, nullptr, 0, 0, nullptr, 0);
    attn_kernel<<<dim3(8, Hh, Bb*Ee), 256, 0, stream>>>(
        qkv_all, mask, ctx_all, (long)MROWS*QKVN, (long)MROWS*Dd);
    gemm_bt<1><<<dim3(Dd/128, MROWS/128, Ee), 256, 0, stream>>>(
        ctx_all, Wdb, nullptr, bd, attall, Dd, Dd,
        (long)MROWS*Dd, (long)Dd*Dd, (long)MROWS*Dd, Dd, nullptr, 0, 0, feat, 0);

    routing_kernel<<<1, 64, 0, stream>>>(feat, centers, sel);
    hprep_kernel<<<MROWS/4, 256, 0, stream>>>(attall, x, ln1g, ln1b, sel, hbuf);
    gemm_bt<2><<<dim3(DFF/128, MROWS/128, 1), 256, 0, stream>>>(
        hbuf, nullptr, W1, b1, Gbuf, Dd, DFF,
        0, 0, 0, 0, sel, (long)DFF*Dd, DFF, nullptr, 0);
    gemm_bt<3><<<dim3(Dd/128, MROWS/128, 1), 256, 0, stream>>>(
        Gbuf, nullptr, W2, b2, tbuf, DFF, Dd,
        0, 0, 0, 0, sel, (long)Dd*DFF, Dd, nullptr, 0);
    ln2_kernel<<<MROWS/4, 256, 0, stream>>>(hbuf, tbuf, ln2g, ln2b, sel, (float*)d_out);
  } else {
    unsigned short* qkvbuf = (unsigned short*)carve((size_t)MROWS*QKVN*2);    // 18.9 MB
    unsigned short* ctxbuf = (unsigned short*)carve((size_t)MROWS*Dd*2);      // 6.3 MB
    unsigned short* Gbuf   = (unsigned short*)carve((size_t)MROWS*DFF*2);     // 25.2 MB
    float* tbuf = (float*)qkvbuf;

    for (int e=0; e<Ee; e++){
      gemm_bt<0><<<dim3(QKVN/128, MROWS/128, 1), 256, 0, stream>>>(
          xb, Wqkvb + (long)e*QKVN*Dd, nullptr, nullptr, qkvbuf, Dd, QKVN,
          0, 0, 0, 0, nullptr, 0, 0, nullptr, 0);
      attn_kernel<<<dim3(8, Hh, Bb), 256, 0, stream>>>(qkvbuf, mask, ctxbuf, 0, 0);
      gemm_bt<1><<<dim3(Dd/128, MROWS/128, 1), 256, 0, stream>>>(
          ctxbuf, Wdb + (long)e*Dd*Dd, nullptr, bd + (long)e*Dd,
          (void*)(attall + (long)e*MROWS*Dd), Dd, Dd,
          0, 0, 0, 0, nullptr, 0, 0, feat, e);
    }

    routing_kernel<<<1, 64, 0, stream>>>(feat, centers, sel);
    hprep_kernel<<<MROWS/4, 256, 0, stream>>>(attall, x, ln1g, ln1b, sel, hbuf);
    gemm_bt<2><<<dim3(DFF/128, MROWS/128, 1), 256, 0, stream>>>(
        hbuf, nullptr, W1, b1, Gbuf, Dd, DFF,
        0, 0, 0, 0, sel, (long)DFF*Dd, DFF, nullptr, 0);
    gemm_bt<3><<<dim3(Dd/128, MROWS/128, 1), 256, 0, stream>>>(
        Gbuf, nullptr, W2, b2, tbuf, DFF, Dd,
        0, 0, 0, 0, sel, (long)Dd*DFF, Dd, nullptr, 0);
    ln2_kernel<<<MROWS/4, 256, 0, stream>>>(hbuf, tbuf, ln2g, ln2b, sel, (float*)d_out);
  }
}

// Round 4
// 823.766 us; speedup vs baseline: 1.3209x; 1.3209x over previous
//
#include <hip/hip_runtime.h>
#include <hip/hip_fp16.h>
#include <math.h>
#include <stdint.h>

#define Bb 8
#define Ss 512
#define Dd 768
#define Hh 12
#define Ee 8
#define DFF 3072
#define MROWS 4096          // B*S
#define QKVN 2304           // H*3*DH

static __device__ const float SCALE_ = 0.036084391824351615f; // 768^-0.5

typedef short bf8_t __attribute__((ext_vector_type(8)));
typedef _Float16 f16x4_t __attribute__((ext_vector_type(4)));
typedef float f32x4_t __attribute__((ext_vector_type(4)));

__device__ __forceinline__ float bf2f(unsigned short u){
  union { unsigned int i; float f; } x; x.i = ((unsigned int)u)<<16; return x.f;
}
__device__ __forceinline__ unsigned short f2bf(float f){
  union { float f; unsigned int i; } x; x.f = f;
  unsigned int u = x.i;
  return (unsigned short)((u + 0x7fffu + ((u>>16)&1u)) >> 16);
}

// async global->LDS, 16B per lane; LDS dest is wave-uniform base + lane*16
__device__ __forceinline__ void gl_lds16(const void* g, void* l){
  __builtin_amdgcn_global_load_lds(
      (const __attribute__((address_space(1))) unsigned int*)(g),
      (__attribute__((address_space(3))) unsigned int*)(uintptr_t)(l),
      16, 0, 0);
}

// ---------------- cast fp32 -> bf16 (n % 4 == 0) ----------------
__global__ void cast_kernel(const float* __restrict__ in, unsigned short* __restrict__ out, int n){
  int i = (blockIdx.x*256 + threadIdx.x)*4;
  if (i >= n) return;
  const float4 v = *(const float4*)(in + i);
  ushort4 o; o.x=f2bf(v.x); o.y=f2bf(v.y); o.z=f2bf(v.z); o.w=f2bf(v.w);
  *(ushort4*)(out + i) = o;
}

// ---------------- GEMM: C = A(MxK) * B(NxK)^T, 128x128 tile, 4 waves ----------------
// MODE 0: B bf16 (z-indexed),  no bias,        store bf16   (QKV, chunked over experts)
// MODE 1: A+B bf16 (sel-idx),  bias,           store bf16   (dense for selected experts)
// MODE 2: B fp32 (sel-idx),    bias, GELU,     store bf16   (FFN1)
// MODE 3: B fp32 (sel-idx),    bias,           store fp32   (FFN2)
// swz: 0 none; 1 expert-per-XCD (needs gridDim.z==8); 2 batch-per-XCD (gridDim.y==32,z==1)
template<int MODE>
__global__ __launch_bounds__(256)
void gemm_bt(const unsigned short* __restrict__ A,
             const unsigned short* __restrict__ Bbf,
             const float* __restrict__ Bf32,
             const float* __restrict__ bias,
             void* __restrict__ Cout,
             int K, int N,
             long bStrideZ, long cStrideZ,
             const int* __restrict__ sel,
             long selAStride, long selBStride, int selBiasStride,
             int swz)
{
  constexpr int BP = (MODE >= 2) ? 40 : 32;
  __shared__ unsigned short As[128*32];
  __shared__ unsigned short Bs[128*BP];

  int rt, ct, zz;
  if (swz == 1) {
    const int id = (blockIdx.z*gridDim.y + blockIdx.y)*gridDim.x + blockIdx.x;
    const int xcd = id & 7, slot = id >> 3;
    zz = xcd; ct = slot % gridDim.x; rt = slot / gridDim.x;
  } else if (swz == 2) {
    const int id = blockIdx.y*gridDim.x + blockIdx.x;
    const int xcd = id & 7, slot = id >> 3;
    rt = xcd*4 + (slot & 3); ct = slot >> 2; zz = 0;
  } else {
    rt = blockIdx.y; ct = blockIdx.x; zz = blockIdx.z;
  }

  const int t = threadIdx.x;
  const int w = t>>6, l = t&63, q4 = l>>4, mr = l&15;
  const int wm = (w&1)*64, wn = (w>>1)*64;
  const int sr = t>>2, cv = t&3;

  const unsigned short* Ap = A;
  const unsigned short* Bp = Bbf;
  const float* Bf_ = Bf32;
  const float* biasp = bias;
  if (MODE == 0) {
    Bp += (size_t)zz * bStrideZ;
  } else {
    const int ex = sel[rt>>2];
    if (MODE == 1) { Ap += (size_t)ex * selAStride; Bp += (size_t)ex * selBStride; }
    else           { Bf_ += (size_t)ex * selBStride; }
    biasp += (long)ex * selBiasStride;
  }

  f32x4_t acc[4][4];
  #pragma unroll
  for (int i=0;i<4;i++)
    #pragma unroll
    for (int j=0;j<4;j++) acc[i][j] = (f32x4_t){0.f,0.f,0.f,0.f};

  // staging addresses (per-lane global, per-wave LDS base)
  const unsigned short* gA = Ap + (size_t)(rt*128 + w*16 + (l>>2))*K + (l&3)*8;
  unsigned short* lA = As + w*512;   // w*1024 bytes
  const unsigned short* gB = nullptr;
  unsigned short* lB = Bs + w*512;
  if (MODE < 2) gB = Bp + (size_t)(ct*128 + w*16 + (l>>2))*K + (l&3)*8;

  for (int k0 = 0; k0 < K; k0 += 32) {
    uint4 b0, b1;
    if (MODE >= 2) {
      const float* Br0 = Bf_ + (long)(ct*128 + sr)*K + cv*8 + k0;
      const float* Br1 = Br0 + (long)64*K;
      float4 f0a = *(const float4*)Br0;  float4 f0b = *(const float4*)(Br0+4);
      float4 f1a = *(const float4*)Br1;  float4 f1b = *(const float4*)(Br1+4);
      union { unsigned short s[8]; uint4 v; } p0, p1;
      p0.s[0]=f2bf(f0a.x); p0.s[1]=f2bf(f0a.y); p0.s[2]=f2bf(f0a.z); p0.s[3]=f2bf(f0a.w);
      p0.s[4]=f2bf(f0b.x); p0.s[5]=f2bf(f0b.y); p0.s[6]=f2bf(f0b.z); p0.s[7]=f2bf(f0b.w);
      p1.s[0]=f2bf(f1a.x); p1.s[1]=f2bf(f1a.y); p1.s[2]=f2bf(f1a.z); p1.s[3]=f2bf(f1a.w);
      p1.s[4]=f2bf(f1b.x); p1.s[5]=f2bf(f1b.y); p1.s[6]=f2bf(f1b.z); p1.s[7]=f2bf(f1b.w);
      b0 = p0.v; b1 = p1.v;
    }
    __syncthreads();   // previous iteration's frag reads done
    gl_lds16(gA + k0,                lA);
    gl_lds16(gA + (size_t)64*K + k0, lA + 2048);
    if (MODE < 2) {
      gl_lds16(gB + k0,                lB);
      gl_lds16(gB + (size_t)64*K + k0, lB + 2048);
    } else {
      *(uint4*)&Bs[sr*40 + cv*8]      = b0;
      *(uint4*)&Bs[(sr+64)*40 + cv*8] = b1;
    }
    __syncthreads();
    bf8_t af[4], bfv[4];
    #pragma unroll
    for (int i=0;i<4;i++) af[i]  = *(const bf8_t*)&As[(wm+i*16+mr)*32 + q4*8];
    #pragma unroll
    for (int j=0;j<4;j++) bfv[j] = *(const bf8_t*)&Bs[(wn+j*16+mr)*BP + q4*8];
    #pragma unroll
    for (int i=0;i<4;i++)
      #pragma unroll
      for (int j=0;j<4;j++)
        acc[i][j] = __builtin_amdgcn_mfma_f32_16x16x32_bf16(af[i], bfv[j], acc[i][j], 0,0,0);
  }

  const long Cld = N;
  unsigned short* Cb16 = (unsigned short*)Cout + (size_t)zz * cStrideZ;
  float* Cf32 = (float*)Cout;
  #pragma unroll
  for (int j=0;j<4;j++){
    const int n = ct*128 + wn + j*16 + mr;
    const float bv = (MODE==0) ? 0.f : biasp[n];
    #pragma unroll
    for (int i=0;i<4;i++){
      const long mbase = (long)rt*128 + wm + i*16 + q4*4;
      #pragma unroll
      for (int r=0;r<4;r++){
        const float v = acc[i][j][r] + bv;
        const long m = mbase + r;
        if (MODE==0 || MODE==1) {
          Cb16[m*Cld + n] = f2bf(v);
        } else if (MODE==2) {
          const float g = 0.5f*v*(1.0f + erff(v*0.70710678118654752f));
          Cb16[m*Cld + n] = f2bf(g);
        } else {
          Cf32[m*Cld + n] = v;
        }
      }
    }
  }
}

// ---------------- attention: per (qblock 64 rows, head, batch[, expert]) workgroup ----------
__global__ __launch_bounds__(256)
void attn_kernel(const unsigned short* __restrict__ qkv,
                 const int* __restrict__ mask,
                 unsigned short* __restrict__ ctx,
                 long qkvStrideZ, long ctxStrideZ)
{
  const int qb = blockIdx.x, h = blockIdx.y;
  const int zz = blockIdx.z;
  const int b = zz & 7, e = zz >> 3;
  qkv += (size_t)e * qkvStrideZ;
  ctx += (size_t)e * ctxStrideZ;

  const int t = threadIdx.x, w = t>>6, l = t&63, q4 = l>>4, mr = l&15;
  __shared__ unsigned short Ks[16*72];   // 16 keys x 64 d (bf16), pitch 72
  __shared__ unsigned short Vs[64*20];   // V^T: 64 d x 16 keys (f16), pitch 20

  const int srow = b*512 + qb*64 + w*16;
  const unsigned short* qp = qkv + (long)(srow+mr)*QKVN + h*192;
  const bf8_t qf0 = *(const bf8_t*)(qp + q4*8);
  const bf8_t qf1 = *(const bf8_t*)(qp + 32 + q4*8);

  f32x4_t cacc[4];
  #pragma unroll
  for (int d=0; d<4; d++) cacc[d] = (f32x4_t){0.f,0.f,0.f,0.f};
  float lsum = 0.f;

  const int el   = t*4;
  const int skey = el>>6;     // 0..15
  const int sd   = el&63;     // multiple of 4

  for (int kt=0; kt<32; kt++){
    const long krow = (long)(b*512 + kt*16 + skey)*QKVN + h*192;
    const uint2 kv = *(const uint2*)(qkv + krow + 64  + sd);
    const uint2 vv = *(const uint2*)(qkv + krow + 128 + sd);
    __syncthreads();   // previous iteration's LDS reads done
    *(uint2*)&Ks[skey*72 + sd] = kv;
    {
      const unsigned short* pv = (const unsigned short*)&vv;
      #pragma unroll
      for (int jj=0;jj<4;jj++){
        const __half hv = __float2half(bf2f(pv[jj]));
        Vs[(sd+jj)*20 + skey] = __half_as_ushort(hv);
      }
    }
    __syncthreads();

    const bf8_t kf0 = *(const bf8_t*)&Ks[mr*72 + q4*8];
    const bf8_t kf1 = *(const bf8_t*)&Ks[mr*72 + 32 + q4*8];
    f32x4_t st = __builtin_amdgcn_mfma_f32_16x16x32_bf16(kf0, qf0, (f32x4_t){0.f,0.f,0.f,0.f}, 0,0,0);
    st = __builtin_amdgcn_mfma_f32_16x16x32_bf16(kf1, qf1, st, 0,0,0);

    f16x4_t pf;
    #pragma unroll
    for (int r=0;r<4;r++){
      const int key = kt*16 + q4*4 + r;
      float p = __expf(st[r]*SCALE_);
      if (mask[b*512 + key] == 0) p = 0.f;
      lsum += p;
      pf[r] = (_Float16)p;
    }
    #pragma unroll
    for (int dblk=0; dblk<4; dblk++){
      const f16x4_t vf = *(const f16x4_t*)&Vs[(dblk*16+mr)*20 + q4*4];
      cacc[dblk] = __builtin_amdgcn_mfma_f32_16x16x16f16(pf, vf, cacc[dblk], 0,0,0);
    }
  }

  lsum += __shfl_xor(lsum, 16);
  lsum += __shfl_xor(lsum, 32);
  #pragma unroll
  for (int r=0;r<4;r++){
    const int m2 = q4*4 + r;
    const float lr = __shfl(lsum, m2);
    const float inv = 1.0f/lr;
    const long orow = (long)(b*512 + qb*64 + w*16 + m2)*Dd + h*64;
    #pragma unroll
    for (int dblk=0; dblk<4; dblk++){
      ctx[orow + dblk*16 + mr] = f2bf(cacc[dblk][r]*inv);
    }
  }
}

// ---------------- ctxmean: mean over seq of ctx -> (e,b,d) fp32 ----------------
__global__ void ctxmean_kernel(const unsigned short* __restrict__ ctx, float* __restrict__ out){
  const int d = blockIdx.x*256 + threadIdx.x;   // gridDim.x == 3
  const int b = blockIdx.y, e = blockIdx.z;
  const unsigned short* p = ctx + ((size_t)e*MROWS + b*512)*Dd + d;
  float s = 0.f;
  for (int i=0;i<512;i++) s += bf2f(p[(size_t)i*Dd]);
  out[((size_t)e*Bb + b)*Dd + d] = s * (1.0f/512.0f);
}

// ---------------- featgemm: feat[e,b,:] = ctxmean[e,b,:] @ Wd[e]^T + bd[e] ----------------
__global__ __launch_bounds__(256)
void featgemm_kernel(const float* __restrict__ ctxmean, const unsigned short* __restrict__ Wdb,
                     const float* __restrict__ bd, float* __restrict__ feat){
  __shared__ float xs[Dd];
  const int b = blockIdx.x, e = blockIdx.y;
  const int t = threadIdx.x;
  for (int i=t;i<Dd;i+=256) xs[i] = ctxmean[((size_t)e*Bb+b)*Dd + i];
  __syncthreads();
  #pragma unroll
  for (int c0=0;c0<3;c0++){
    const int col = c0*256 + t;
    const unsigned short* wr = Wdb + ((size_t)e*Dd + col)*Dd;
    float s = 0.f;
    for (int k=0;k<Dd;k+=8){
      bf8_t wv = *(const bf8_t*)(wr + k);
      const unsigned short* wp = (const unsigned short*)&wv;
      #pragma unroll
      for (int j=0;j<8;j++) s += bf2f(wp[j]) * xs[k+j];
    }
    feat[((size_t)e*Bb+b)*Dd + col] = s + bd[(size_t)e*Dd + col];
  }
}

// ---------------- routing: dists + argmin ----------------
__global__ void routing_kernel(const float* __restrict__ feat, const float* __restrict__ centers,
                               int* __restrict__ sel)
{
  __shared__ float d2s[64];
  const int t = threadIdx.x;
  if (t < 64){
    const int e = t>>3, b = t&7;
    const float* f = feat + (long)(e*Bb + b)*Dd;
    const float* c = centers + (long)e*Dd;
    float s = 0.f;
    for (int d=0; d<Dd; d++){
      const float df = f[d] - c[d];
      s += df*df;
    }
    d2s[t] = s;
  }
  __syncthreads();
  if (t < 8){
    float best = 3.4e38f; int bi = 0;
    for (int e=0;e<8;e++){ const float v = d2s[e*8+t]; if (v < best){ best=v; bi=e; } }
    sel[t] = bi;
  }
}

// ---------------- h = LN1(attsel+x), one wave per row ----------------
__global__ __launch_bounds__(256)
void hprep_kernel(const unsigned short* __restrict__ attsel, const float* __restrict__ x,
                  const float* __restrict__ g, const float* __restrict__ be,
                  const int* __restrict__ sel, unsigned short* __restrict__ hbuf)
{
  const int w = threadIdx.x>>6, l = threadIdx.x&63;
  const int row = blockIdx.x*4 + w;
  const int b = row>>9;
  const int e = sel[b];
  const unsigned short* ap = attsel + (long)row*Dd;
  const float* xp = x + (long)row*Dd;
  float v[12]; float s = 0.f;
  #pragma unroll
  for (int i=0;i<12;i++){ const int d = i*64 + l; v[i] = bf2f(ap[d]) + xp[d]; s += v[i]; }
  #pragma unroll
  for (int o=32;o>0;o>>=1) s += __shfl_xor(s, o);
  const float mean = s * (1.0f/768.0f);
  float vs = 0.f;
  #pragma unroll
  for (int i=0;i<12;i++){ const float dd = v[i]-mean; vs += dd*dd; }
  #pragma unroll
  for (int o=32;o>0;o>>=1) vs += __shfl_xor(vs, o);
  const float rs = rsqrtf(vs*(1.0f/768.0f) + 1e-12f);
  #pragma unroll
  for (int i=0;i<12;i++){
    const int d = i*64 + l;
    hbuf[(long)row*Dd + d] = f2bf((v[i]-mean)*rs*g[(long)e*Dd+d] + be[(long)e*Dd+d]);
  }
}

// ---------------- out = LN2(h + ffn), one wave per row ----------------
__global__ __launch_bounds__(256)
void ln2_kernel(const unsigned short* __restrict__ hbuf, const float* __restrict__ tbuf,
                const float* __restrict__ g, const float* __restrict__ be,
                const int* __restrict__ sel, float* __restrict__ out)
{
  const int w = threadIdx.x>>6, l = threadIdx.x&63;
  const int row = blockIdx.x*4 + w;
  const int b = row>>9;
  const int e = sel[b];
  const unsigned short* hp = hbuf + (long)row*Dd;
  const float* tp = tbuf + (long)row*Dd;
  float v[12]; float s = 0.f;
  #pragma unroll
  for (int i=0;i<12;i++){ const int d = i*64 + l; v[i] = bf2f(hp[d]) + tp[d]; s += v[i]; }
  #pragma unroll
  for (int o=32;o>0;o>>=1) s += __shfl_xor(s, o);
  const float mean = s * (1.0f/768.0f);
  float vs = 0.f;
  #pragma unroll
  for (int i=0;i<12;i++){ const float dd = v[i]-mean; vs += dd*dd; }
  #pragma unroll
  for (int o=32;o>0;o>>=1) vs += __shfl_xor(vs, o);
  const float rs = rsqrtf(vs*(1.0f/768.0f) + 1e-12f);
  #pragma unroll
  for (int i=0;i<12;i++){
    const int d = i*64 + l;
    out[(long)row*Dd + d] = (v[i]-mean)*rs*g[(long)e*Dd+d] + be[(long)e*Dd+d];
  }
}

// ---------------- launch ----------------
extern "C" void kernel_launch(void* const* d_in, const int* in_sizes, int n_in,
                              void* d_out, int out_size, void* d_ws, size_t ws_size,
                              hipStream_t stream)
{
  const float* x      = (const float*)d_in[0];
  const int*   mask   = (const int*)d_in[1];
  const float* Wqkv   = (const float*)d_in[2];
  const float* Wd     = (const float*)d_in[3];
  const float* bd     = (const float*)d_in[4];
  const float* ln1g   = (const float*)d_in[5];
  const float* ln1b   = (const float*)d_in[6];
  const float* W1     = (const float*)d_in[7];
  const float* b1     = (const float*)d_in[8];
  const float* W2     = (const float*)d_in[9];
  const float* b2     = (const float*)d_in[10];
  const float* ln2g   = (const float*)d_in[11];
  const float* ln2b   = (const float*)d_in[12];
  const float* centers= (const float*)d_in[13];

  // tier: pure function of ws_size (constant per session) -> graph-capture safe
  // totals: fixed 107,348,224 + zc*18,874,368*... see carve order below
  int zc;
  if      (ws_size >= 258347264ull) zc = 8;   // 258,343,168 + pad
  else if (ws_size >= 182849792ull) zc = 4;
  else if (ws_size >= 145101056ull) zc = 2;
  else                              zc = 1;

  char* p = (char*)d_ws;
  auto carve = [&](size_t bytes)->char*{ char* r = p; p += ((bytes + 255) & ~(size_t)255); return r; };

  unsigned short* xb      = (unsigned short*)carve((size_t)MROWS*Dd*2);        // 6.3 MB
  unsigned short* Wqkvb   = (unsigned short*)carve((size_t)Ee*QKVN*Dd*2);      // 28.3 MB
  unsigned short* Wdb     = (unsigned short*)carve((size_t)Ee*Dd*Dd*2);        // 9.4 MB
  float*          ctxmean = (float*)carve((size_t)Ee*Bb*Dd*4);                 // 0.2 MB
  float*          feat    = (float*)carve((size_t)Ee*Bb*Dd*4);                 // 0.2 MB
  int*            sel     = (int*)carve(256);
  unsigned short* hbuf    = (unsigned short*)carve((size_t)MROWS*Dd*2);        // 6.3 MB
  unsigned short* attsel  = (unsigned short*)carve((size_t)MROWS*Dd*2);        // 6.3 MB
  unsigned short* qkvchk  = (unsigned short*)carve((size_t)zc*MROWS*QKVN*2);   // zc*18.9 MB
  unsigned short* ctx_all = (unsigned short*)carve((size_t)Ee*MROWS*Dd*2);     // 50.3 MB
  // aliases (lifetimes disjoint):
  unsigned short* Gbuf = attsel;        // FFN1 out: 25.2 MB over attsel+qkvchk (both dead)
  float*          tbuf = (float*)ctx_all; // FFN2 out: 12.6 MB over ctx_all (dead)

  cast_kernel<<<(MROWS*Dd/4 + 255)/256, 256, 0, stream>>>(x, xb, MROWS*Dd);
  cast_kernel<<<(Ee*QKVN*Dd/4 + 255)/256, 256, 0, stream>>>(Wqkv, Wqkvb, Ee*QKVN*Dd);
  cast_kernel<<<(Ee*Dd*Dd/4 + 255)/256, 256, 0, stream>>>(Wd, Wdb, Ee*Dd*Dd);

  const int nchunk = Ee / zc;
  for (int c = 0; c < nchunk; c++){
    gemm_bt<0><<<dim3(QKVN/128, MROWS/128, zc), 256, 0, stream>>>(
        xb, Wqkvb + (size_t)c*zc*QKVN*Dd, nullptr, nullptr, qkvchk,
        Dd, QKVN, (long)QKVN*Dd, (long)MROWS*QKVN,
        nullptr, 0, 0, 0, (zc==8) ? 1 : 0);
    attn_kernel<<<dim3(8, Hh, Bb*zc), 256, 0, stream>>>(
        qkvchk, mask, ctx_all + (size_t)c*zc*MROWS*Dd,
        (long)MROWS*QKVN, (long)MROWS*Dd);
    ctxmean_kernel<<<dim3(3, Bb, zc), 256, 0, stream>>>(
        ctx_all + (size_t)c*zc*MROWS*Dd, ctxmean + (size_t)c*zc*Bb*Dd);
  }

  featgemm_kernel<<<dim3(Bb, Ee), 256, 0, stream>>>(ctxmean, Wdb, bd, feat);
  routing_kernel<<<1, 64, 0, stream>>>(feat, centers, sel);

  // dense only for selected experts: attsel = ctx[sel[b]] @ Wd[sel[b]]^T + bd
  gemm_bt<1><<<dim3(Dd/128, MROWS/128, 1), 256, 0, stream>>>(
      ctx_all, Wdb, nullptr, bd, attsel, Dd, Dd, 0, 0,
      sel, (long)MROWS*Dd, (long)Dd*Dd, Dd, 2);

  hprep_kernel<<<MROWS/4, 256, 0, stream>>>(attsel, x, ln1g, ln1b, sel, hbuf);
  gemm_bt<2><<<dim3(DFF/128, MROWS/128, 1), 256, 0, stream>>>(
      hbuf, nullptr, W1, b1, Gbuf, Dd, DFF, 0, 0,
      sel, 0, (long)DFF*Dd, DFF, 2);
  gemm_bt<3><<<dim3(Dd/128, MROWS/128, 1), 256, 0, stream>>>(
      Gbuf, nullptr, W2, b2, tbuf, DFF, Dd, 0, 0,
      sel, 0, (long)Dd*DFF, Dd, 2);
  ln2_kernel<<<MROWS/4, 256, 0, stream>>>(hbuf, tbuf, ln2g, ln2b, sel, (float*)d_out);
}